// Round 1
// baseline (388.825 us; speedup 1.0000x reference)
//
#include <hip/hip_runtime.h>

// Grid ND sample (bilinear), B=16 H=128 W=128 C=256 P=8192, fp32.
// One wave per sample point; lane i handles float4 channel-chunk i (C=256 =
// 64 lanes x 4 floats). All corner reads and the output store are exactly
// 1 KiB contiguous per wave -> fully coalesced.

#define B_ 16
#define H_ 128
#define W_ 128
#define C_ 256
#define P_ 8192

__global__ __launch_bounds__(256) void grid_sample_kernel(
    const float* __restrict__ in, const float* __restrict__ idx,
    float* __restrict__ out)
{
    const int lane   = threadIdx.x & 63;
    const int sample = (blockIdx.x << 2) + (threadIdx.x >> 6);  // 0 .. B*P-1
    const int b      = sample >> 13;                            // P = 2^13

    // All 64 lanes load the same float2 -> one broadcast transaction.
    const float2 ind = ((const float2*)idx)[sample];

    const float f0 = floorf(ind.x);   // H-dim
    const float f1 = floorf(ind.y);   // W-dim
    const int i0f = (int)f0;
    const int i1f = (int)f1;
    const int i0c = (int)ceilf(ind.x);
    const int i1c = (int)ceilf(ind.y);
    const float mx = ind.x - f0;      // mu_x (H frac)
    const float my = ind.y - f1;      // mu_y (W frac)

    // out = p1*(1-mx)(1-my) + p2*mx(1-my) + p3*(1-mx)my + p4*mx*my
    const float w00 = (1.f - mx) * (1.f - my);
    const float w10 = mx * (1.f - my);
    const float w01 = (1.f - mx) * my;
    const float w11 = mx * my;

    const int bbase = b * (H_ * W_);
    const float4* p1 = (const float4*)(in + (size_t)(bbase + i0f * W_ + i1f) * C_);
    const float4* p2 = (const float4*)(in + (size_t)(bbase + i0c * W_ + i1f) * C_);
    const float4* p3 = (const float4*)(in + (size_t)(bbase + i0f * W_ + i1c) * C_);
    const float4* p4 = (const float4*)(in + (size_t)(bbase + i0c * W_ + i1c) * C_);
    float4*       o  = (float4*)(out + (size_t)sample * C_);

    const float4 v1 = p1[lane];
    const float4 v2 = p2[lane];
    const float4 v3 = p3[lane];
    const float4 v4 = p4[lane];

    float4 r;
    r.x = v1.x * w00 + v2.x * w10 + v3.x * w01 + v4.x * w11;
    r.y = v1.y * w00 + v2.y * w10 + v3.y * w01 + v4.y * w11;
    r.z = v1.z * w00 + v2.z * w10 + v3.z * w01 + v4.z * w11;
    r.w = v1.w * w00 + v2.w * w10 + v3.w * w01 + v4.w * w11;
    o[lane] = r;
}

extern "C" void kernel_launch(void* const* d_in, const int* in_sizes, int n_in,
                              void* d_out, int out_size, void* d_ws, size_t ws_size,
                              hipStream_t stream) {
    const float* in  = (const float*)d_in[0];   // (B,H,W,C) fp32
    const float* idx = (const float*)d_in[1];   // (B,P,2)   fp32
    float* out = (float*)d_out;                 // (B,P,C)   fp32

    const int n_samples = B_ * P_;              // 131072
    dim3 grid(n_samples / 4);                   // 4 waves (samples) per block
    dim3 block(256);
    grid_sample_kernel<<<grid, block, 0, stream>>>(in, idx, out);
}